// Round 9
// baseline (496.615 us; speedup 1.0000x reference)
//
#include <hip/hip_runtime.h>

#define NROW 10000
#define NF 256
#define KF 512
#define MP 10048   // 157*64, padded row/K extent
#define NTILES 157
#define KSPLIT 8
#define CCH 2512   // cols per chunk in k_prep (MP/4)

typedef __attribute__((ext_vector_type(8))) short short8x;
typedef __attribute__((ext_vector_type(4))) float f32x4;

__device__ __forceinline__ unsigned int bf16rne(float f){
  unsigned int u = __builtin_bit_cast(unsigned int, f);
  u += 0x7fffu + ((u >> 16) & 1u);   // round-to-nearest-even
  return u >> 16;
}

// ---------------- Kernel 0: zero d_out (atomic accumulation target)
__global__ void k_zero(float4* __restrict__ p){
  p[blockIdx.x * 256 + threadIdx.x] = make_float4(0.f, 0.f, 0.f, 0.f);
}

// ---------------- k_prep (UNCHANGED from R8): one parallel sweep of adj.
__global__ __launch_bounds__(256) void k_prep(const float* __restrict__ adj,
        unsigned short* __restrict__ adjb, float* __restrict__ degp){
  int t = threadIdx.x;
  int lane = t & 63;
  int row = blockIdx.x * 4 + (t >> 6);
  int cy = blockIdx.y;
  int c0 = cy * CCH;
  int limit = (cy < 3) ? 628 : 616;   // valid f32x4 slots in this chunk
  const f32x4* src = (const f32x4*)(adj + (size_t)row * NROW + c0);
  unsigned short* dst = adjb + (size_t)row * MP + c0;
  const f32x4 zero4 = {0.f, 0.f, 0.f, 0.f};

  f32x4 v[5][2];
  #pragma unroll
  for (int it = 0; it < 4; ++it){
    int fi = it * 128 + lane * 2;
    v[it][0] = __builtin_nontemporal_load(src + fi);
    v[it][1] = __builtin_nontemporal_load(src + fi + 1);
  }
  {
    int fi = 512 + lane * 2;
    v[4][0] = (fi     < limit) ? __builtin_nontemporal_load(src + fi)     : zero4;
    v[4][1] = (fi + 1 < limit) ? __builtin_nontemporal_load(src + fi + 1) : zero4;
  }

  float s = 0.f;
  #pragma unroll
  for (int it = 0; it < 5; ++it){
    int fi0 = it * 128 + lane * 2;
    uint4 o;
    #pragma unroll
    for (int j = 0; j < 2; ++j){
      f32x4 w = v[it][j];
      int gc = c0 + (fi0 + j) * 4;
      if (row == gc    ) w[0] = 1.f;    // diag patch
      if (row == gc + 1) w[1] = 1.f;
      if (row == gc + 2) w[2] = 1.f;
      if (row == gc + 3) w[3] = 1.f;
      s += (w[0] + w[1]) + (w[2] + w[3]);
      unsigned int lo = bf16rne(w[0]) | (bf16rne(w[1]) << 16);
      unsigned int hi = bf16rne(w[2]) | (bf16rne(w[3]) << 16);
      if (j == 0){ o.x = lo; o.y = hi; } else { o.z = lo; o.w = hi; }
    }
    if (it < 4 || fi0 < 628)            // stay inside this chunk's 628 slots
      *(uint4*)(dst + fi0 * 4) = o;
  }
  #pragma unroll
  for (int off = 32; off; off >>= 1) s += __shfl_down(s, off);
  if (lane == 0) degp[cy * MP + row] = s;
}

// ---------------- k_dinv: dinv from partials; also zero hsT K-tail rows
__global__ void k_dinv(const float* __restrict__ degp, float* __restrict__ dinv,
                       unsigned short* __restrict__ hsT){
  int i = blockIdx.x * 256 + threadIdx.x;
  if (i >= MP) return;
  float d = 0.f;
  if (i < NROW){
    float tot = (degp[i] + degp[MP + i]) + (degp[2*MP + i] + degp[3*MP + i]);
    d = tot > 0.f ? rsqrtf(tot) : 0.f;
  }
  dinv[i] = d;
  if (i < NF){                 // zero hsT[i][10000..10048): B K-tail for gemm
    unsigned int* tz = (unsigned int*)(hsT + (size_t)i * MP + NROW);
    #pragma unroll
    for (int m = 0; m < (MP - NROW) / 2; ++m) tz[m] = 0u;
  }
}

// ---------------- k_featw: hsT[c][i] = bf16(dinv[i]*(feat@W)[i][c])  (UNCHANGED)
__global__ __launch_bounds__(128) void k_featw(const float* __restrict__ feat,
        const float* __restrict__ W, const float* __restrict__ dinv,
        unsigned short* __restrict__ hsT){
  __shared__ __align__(16) float fs[8][512];   // 16 KB
  int t = threadIdx.x;        // 0..127
  int i0 = blockIdx.x * 8;    // 1250*8 = 10000 exact
  #pragma unroll
  for (int it = 0; it < 8; ++it){
    int idx = it * 128 + t;
    int r = idx >> 7, c4 = (idx & 127) * 4;
    *(float4*)&fs[r][c4] = *(const float4*)(feat + (size_t)(i0 + r) * KF + c4);
  }
  __syncthreads();
  float acc[8][2];
  #pragma unroll
  for (int r = 0; r < 8; ++r){ acc[r][0] = 0.f; acc[r][1] = 0.f; }
  int c0 = t, c1 = t + 128;
  for (int k = 0; k < KF; k += 4){
    const float* Wk = W + (size_t)k * NF;
    float w0a = Wk[c0],        w0b = Wk[c1];
    float w1a = Wk[NF + c0],   w1b = Wk[NF + c1];
    float w2a = Wk[2*NF + c0], w2b = Wk[2*NF + c1];
    float w3a = Wk[3*NF + c0], w3b = Wk[3*NF + c1];
    #pragma unroll
    for (int r = 0; r < 8; ++r){
      float4 f = *(const float4*)&fs[r][k];
      float a0 = acc[r][0], a1 = acc[r][1];
      a0 = fmaf(f.x, w0a, a0); a1 = fmaf(f.x, w0b, a1);
      a0 = fmaf(f.y, w1a, a0); a1 = fmaf(f.y, w1b, a1);
      a0 = fmaf(f.z, w2a, a0); a1 = fmaf(f.z, w2b, a1);
      a0 = fmaf(f.w, w3a, a0); a1 = fmaf(f.w, w3b, a1);
      acc[r][0] = a0; acc[r][1] = a1;
    }
  }
  float dv[8];
  #pragma unroll
  for (int r = 0; r < 8; ++r) dv[r] = dinv[i0 + r];
  unsigned short* d0 = hsT + (size_t)c0 * MP + i0;
  unsigned short* d1 = hsT + (size_t)c1 * MP + i0;
  #pragma unroll
  for (int r = 0; r < 8; r += 2){
    unsigned int u0 = bf16rne(acc[r][0] * dv[r]) | (bf16rne(acc[r+1][0] * dv[r+1]) << 16);
    unsigned int u1 = bf16rne(acc[r][1] * dv[r]) | (bf16rne(acc[r+1][1] * dv[r+1]) << 16);
    *(unsigned int*)(d0 + r) = u0;
    *(unsigned int*)(d1 + r) = u1;
  }
}

// ---------------- k_gemm (RESTRUCTURED): out += adjb @ hs
// K split 8-ways (grid 157x8) + register-prefetch 2-phase pipeline:
// next tile's global->reg loads issue right after the first barrier and
// hide under ds_read+MFMA; they're written to LDS next iteration.
__global__ __launch_bounds__(256, 3) void k_gemm(const unsigned short* __restrict__ adjb,
        const unsigned short* __restrict__ hsT, float* __restrict__ out){
  __shared__ __align__(16) unsigned short Al[64][72];    // +8 pad: 144B stride
  __shared__ __align__(16) unsigned short Bl[256][72];
  int t = threadIdx.x;
  int lane = t & 63, wid = t >> 6;
  int wr = wid >> 1, wc = wid & 1;      // 2x2 waves, wave tile 32x128
  int r0 = blockIdx.x * 64;
  int by = blockIdx.y;                  // K chunks: 7x20 + 1x17 tiles
  int kt0 = by * 20;
  int kt1 = (by == KSPLIT - 1) ? NTILES : kt0 + 20;

  f32x4 acc[2][8];
  #pragma unroll
  for (int a = 0; a < 2; ++a)
    #pragma unroll
    for (int b = 0; b < 8; ++b)
      #pragma unroll
      for (int j = 0; j < 4; ++j) acc[a][b][j] = 0.f;

  int arow = t >> 3;          // A-stage: 0..31 (x2 groups), col-8 t&7
  int aoff = (t & 7) * 8;
  int bcol = t >> 3;          // 0..31
  int bko  = (t & 7) * 8;     // 0..56

  uint4 a_pf[2], b_pf[8];
  // prologue: prefetch first tile into regs
  {
    int k0 = kt0 * 64;
    #pragma unroll
    for (int it = 0; it < 2; ++it)
      a_pf[it] = *(const uint4*)(adjb + (size_t)(r0 + it*32 + arow) * MP + k0 + aoff);
    #pragma unroll
    for (int it = 0; it < 8; ++it)
      b_pf[it] = *(const uint4*)(hsT + (size_t)(it*32 + bcol) * MP + k0 + bko);
  }

  for (int kt = kt0; kt < kt1; ++kt){
    // phase 1: commit prefetched regs to LDS (vmcnt wait inserted by compiler)
    #pragma unroll
    for (int it = 0; it < 2; ++it)
      *(uint4*)&Al[it*32 + arow][aoff] = a_pf[it];
    #pragma unroll
    for (int it = 0; it < 8; ++it)
      *(uint4*)&Bl[it*32 + bcol][bko] = b_pf[it];
    __syncthreads();
    // phase 2: issue NEXT tile's loads (reg-targeted: cross barriers freely)
    if (kt + 1 < kt1){
      int k0n = (kt + 1) * 64;
      #pragma unroll
      for (int it = 0; it < 2; ++it)
        a_pf[it] = *(const uint4*)(adjb + (size_t)(r0 + it*32 + arow) * MP + k0n + aoff);
      #pragma unroll
      for (int it = 0; it < 8; ++it)
        b_pf[it] = *(const uint4*)(hsT + (size_t)(it*32 + bcol) * MP + k0n + bko);
    }
    // phase 3: ds_read + MFMA on current tile (hides the loads above)
    #pragma unroll
    for (int kk = 0; kk < 64; kk += 32){
      short8x a0 = *(const short8x*)&Al[wr*32      + (lane & 15)][kk + (lane >> 4) * 8];
      short8x a1 = *(const short8x*)&Al[wr*32 + 16 + (lane & 15)][kk + (lane >> 4) * 8];
      #pragma unroll
      for (int ni = 0; ni < 8; ++ni){
        short8x b = *(const short8x*)&Bl[wc*128 + ni*16 + (lane & 15)][kk + (lane >> 4) * 8];
        acc[0][ni] = __builtin_amdgcn_mfma_f32_16x16x32_bf16(a0, b, acc[0][ni], 0, 0, 0);
        acc[1][ni] = __builtin_amdgcn_mfma_f32_16x16x32_bf16(a1, b, acc[1][ni], 0, 0, 0);
      }
    }
    __syncthreads();
  }
  // epilogue: atomic accumulate partial K-sums (8 commutative adds/elem)
  #pragma unroll
  for (int mi = 0; mi < 2; ++mi){
    #pragma unroll
    for (int ni = 0; ni < 8; ++ni){
      int gc = wc*128 + ni*16 + (lane & 15);
      #pragma unroll
      for (int j = 0; j < 4; ++j){
        int gr = r0 + wr*32 + mi*16 + (lane >> 4) * 4 + j;
        if (gr < NROW) atomicAdd(out + (size_t)gr * NF + gc, acc[mi][ni][j]);
      }
    }
  }
}

// ---------------- k_epi: out = relu(dinv_i * acc + cb + eb), in place
__global__ void k_epi(float* __restrict__ out, const float* __restrict__ dinv,
                      const float* __restrict__ cb, const float* __restrict__ eb){
  int e = (blockIdx.x * 256 + threadIdx.x) * 4;
  int i = e >> 8, c = e & 255;
  float di = dinv[i];
  float4 v = *(float4*)(out + e);
  v.x = fmaxf(fmaf(v.x, di, cb[c+0] + eb[c+0]), 0.f);
  v.y = fmaxf(fmaf(v.y, di, cb[c+1] + eb[c+1]), 0.f);
  v.z = fmaxf(fmaf(v.z, di, cb[c+2] + eb[c+2]), 0.f);
  v.w = fmaxf(fmaf(v.w, di, cb[c+3] + eb[c+3]), 0.f);
  *(float4*)(out + e) = v;
}

extern "C" void kernel_launch(void* const* d_in, const int* in_sizes, int n_in,
                              void* d_out, int out_size, void* d_ws, size_t ws_size,
                              hipStream_t stream){
  const float* feat = (const float*)d_in[0];
  const float* adj  = (const float*)d_in[1];
  const float* W    = (const float*)d_in[2];
  const float* cb   = (const float*)d_in[3];
  const float* eb   = (const float*)d_in[4];
  float* out = (float*)d_out;

  float* degp = (float*)d_ws;
  float* dinv = (float*)((char*)d_ws + (256u << 10));
  unsigned short* hsT  = (unsigned short*)((char*)d_ws + (512u << 10));
  unsigned short* adjb = (unsigned short*)((char*)d_ws + (8u << 20));

  k_zero <<<(NROW*NF)/1024,        256, 0, stream>>>((float4*)out);
  k_prep <<<dim3(NROW/4, 4),       256, 0, stream>>>(adj, adjb, degp);
  k_dinv <<<(MP + 255)/256,        256, 0, stream>>>(degp, dinv, hsT);
  k_featw<<<NROW/8,                128, 0, stream>>>(feat, W, dinv, hsT);
  k_gemm <<<dim3(NTILES, KSPLIT),  256, 0, stream>>>(adjb, hsT, out);
  k_epi  <<<(NROW*NF)/1024,        256, 0, stream>>>(out, dinv, cb, eb);
}

// Round 10
// 278.665 us; speedup vs baseline: 1.7821x; 1.7821x over previous
//
#include <hip/hip_runtime.h>

#define NROW 10000
#define NF 256
#define KF 512
#define MP 10048   // 157*64, padded row/K extent
#define NTILES 157
#define CCH 2512   // cols per chunk in k_deg2 (MP/4)

typedef __attribute__((ext_vector_type(8))) short short8x;
typedef __attribute__((ext_vector_type(4))) float f32x4;

__device__ __forceinline__ unsigned int bf16rne(float f){
  unsigned int u = __builtin_bit_cast(unsigned int, f);
  u += 0x7fffu + ((u >> 16) & 1u);   // round-to-nearest-even
  return u >> 16;
}

// ---------------- Kernel 0: zero d_out (atomic accumulation target)
__global__ void k_zero(float4* __restrict__ p){
  p[blockIdx.x * 256 + threadIdx.x] = make_float4(0.f, 0.f, 0.f, 0.f);
}

// ---------------- k_deg2: PURE-READ degree sweep (no adjb, no stores).
// One wave per (row x col-chunk); 10 loads in flight per lane; raw row
// partial sums only (diag correction applied in k_dinv).
__global__ __launch_bounds__(256) void k_deg2(const float* __restrict__ adj,
        float* __restrict__ degp){
  int t = threadIdx.x;
  int lane = t & 63;
  int row = blockIdx.x * 4 + (t >> 6);
  int cy = blockIdx.y;
  int c0 = cy * CCH;
  int limit = (cy < 3) ? 628 : 616;   // valid f32x4 slots in this chunk
  const f32x4* src = (const f32x4*)(adj + (size_t)row * NROW + c0);
  const f32x4 zero4 = {0.f, 0.f, 0.f, 0.f};

  f32x4 v[10];
  #pragma unroll
  for (int it = 0; it < 4; ++it){
    int fi = it * 128 + lane * 2;
    v[2*it]   = src[fi];
    v[2*it+1] = src[fi + 1];
  }
  {
    int fi = 512 + lane * 2;
    v[8] = (fi     < limit) ? src[fi]     : zero4;
    v[9] = (fi + 1 < limit) ? src[fi + 1] : zero4;
  }
  float s0 = 0.f, s1 = 0.f, s2 = 0.f, s3 = 0.f;   // 4 independent chains
  #pragma unroll
  for (int it = 0; it < 10; ++it){
    s0 += v[it][0]; s1 += v[it][1]; s2 += v[it][2]; s3 += v[it][3];
  }
  float s = (s0 + s1) + (s2 + s3);
  #pragma unroll
  for (int off = 32; off; off >>= 1) s += __shfl_down(s, off);
  if (lane == 0) degp[cy * MP + row] = s;   // unique slot: deterministic
}

// ---------------- k_dinv: dinv[i] = rsqrt(rawsum - adj[i][i] + 1);
// also zeroes hsT K-tail rows [10000,10048) for the gemm B-operand.
__global__ void k_dinv(const float* __restrict__ degp, const float* __restrict__ adj,
                       float* __restrict__ dinv, unsigned short* __restrict__ hsT){
  int i = blockIdx.x * 256 + threadIdx.x;
  if (i >= MP) return;
  float d = 0.f;
  if (i < NROW){
    float tot = (degp[i] + degp[MP + i]) + (degp[2*MP + i] + degp[3*MP + i]);
    tot += 1.0f - adj[(size_t)i * NROW + i];   // diag patched to 1
    d = tot > 0.f ? rsqrtf(tot) : 0.f;
  }
  dinv[i] = d;
  if (i < NF){
    unsigned int* tz = (unsigned int*)(hsT + (size_t)i * MP + NROW);
    #pragma unroll
    for (int m = 0; m < (MP - NROW) / 2; ++m) tz[m] = 0u;
  }
}

// ---------------- k_featw: hsT[c][i] = bf16(dinv[i]*(feat@W)[i][c])  (UNCHANGED)
__global__ __launch_bounds__(128) void k_featw(const float* __restrict__ feat,
        const float* __restrict__ W, const float* __restrict__ dinv,
        unsigned short* __restrict__ hsT){
  __shared__ __align__(16) float fs[8][512];   // 16 KB
  int t = threadIdx.x;        // 0..127
  int i0 = blockIdx.x * 8;    // 1250*8 = 10000 exact
  #pragma unroll
  for (int it = 0; it < 8; ++it){
    int idx = it * 128 + t;
    int r = idx >> 7, c4 = (idx & 127) * 4;
    *(float4*)&fs[r][c4] = *(const float4*)(feat + (size_t)(i0 + r) * KF + c4);
  }
  __syncthreads();
  float acc[8][2];
  #pragma unroll
  for (int r = 0; r < 8; ++r){ acc[r][0] = 0.f; acc[r][1] = 0.f; }
  int c0 = t, c1 = t + 128;
  for (int k = 0; k < KF; k += 4){
    const float* Wk = W + (size_t)k * NF;
    float w0a = Wk[c0],        w0b = Wk[c1];
    float w1a = Wk[NF + c0],   w1b = Wk[NF + c1];
    float w2a = Wk[2*NF + c0], w2b = Wk[2*NF + c1];
    float w3a = Wk[3*NF + c0], w3b = Wk[3*NF + c1];
    #pragma unroll
    for (int r = 0; r < 8; ++r){
      float4 f = *(const float4*)&fs[r][k];
      float a0 = acc[r][0], a1 = acc[r][1];
      a0 = fmaf(f.x, w0a, a0); a1 = fmaf(f.x, w0b, a1);
      a0 = fmaf(f.y, w1a, a0); a1 = fmaf(f.y, w1b, a1);
      a0 = fmaf(f.z, w2a, a0); a1 = fmaf(f.z, w2b, a1);
      a0 = fmaf(f.w, w3a, a0); a1 = fmaf(f.w, w3b, a1);
      acc[r][0] = a0; acc[r][1] = a1;
    }
  }
  float dv[8];
  #pragma unroll
  for (int r = 0; r < 8; ++r) dv[r] = dinv[i0 + r];
  unsigned short* d0 = hsT + (size_t)c0 * MP + i0;
  unsigned short* d1 = hsT + (size_t)c1 * MP + i0;
  #pragma unroll
  for (int r = 0; r < 8; r += 2){
    unsigned int u0 = bf16rne(acc[r][0] * dv[r]) | (bf16rne(acc[r+1][0] * dv[r+1]) << 16);
    unsigned int u1 = bf16rne(acc[r][1] * dv[r]) | (bf16rne(acc[r+1][1] * dv[r+1]) << 16);
    *(unsigned int*)(d0 + r) = u0;
    *(unsigned int*)(d1 + r) = u1;
  }
}

// ---------------- k_gemm (REVERT to measured-known-good R2 form):
// out += Ahat_bf16 @ hs, A staged from f32 adj with inline convert+diag
// patch. K split 4-ways, atomic accumulate. No reg-prefetch pipeline
// (R9 lesson: __syncthreads drains vmcnt -> pipeline is void in HIP).
__global__ __launch_bounds__(256, 2) void k_gemm(const float* __restrict__ adj,
        const unsigned short* __restrict__ hsT, float* __restrict__ out){
  __shared__ __align__(16) unsigned short Al[64][72];    // +8 pad: 144B stride
  __shared__ __align__(16) unsigned short Bl[256][72];
  int t = threadIdx.x;
  int lane = t & 63, wid = t >> 6;
  int wr = wid >> 1, wc = wid & 1;      // 2x2 waves, wave tile 32x128
  int r0 = blockIdx.x * 64;
  int by = blockIdx.y;                  // K chunks of {40,39,39,39} tiles
  int kt0 = by * 39 + (by > 0 ? 1 : 0);
  int kt1 = (by + 1) * 39 + 1;

  f32x4 acc[2][8];
  #pragma unroll
  for (int a = 0; a < 2; ++a)
    #pragma unroll
    for (int b = 0; b < 8; ++b)
      #pragma unroll
      for (int j = 0; j < 4; ++j) acc[a][b][j] = 0.f;

  int arow = t >> 4;          // 0..15
  int acol = (t & 15) * 4;    // 0..60
  int bcol = t >> 3;          // 0..31
  int bko  = (t & 7) * 8;     // 0..56

  for (int kt = kt0; kt < kt1; ++kt){
    int k0 = kt * 64;
    // ---- stage A tile (f32 -> bf16, diagonal patched, addr-clamped tail)
    #pragma unroll
    for (int it = 0; it < 4; ++it){
      int row = it * 16 + arow;
      int gr  = r0 + row;
      int gcb = k0 + acol;
      int er = gr  < NROW      ? gr  : NROW - 1;   // pad rows discarded at store
      int ec = gcb <= NROW - 4 ? gcb : NROW - 4;   // tail cols multiply B==0
      float4 v = *(const float4*)(adj + (size_t)er * NROW + ec);
      float f0 = v.x, f1 = v.y, f2 = v.z, f3 = v.w;
      if (gr == gcb    ) f0 = 1.f;
      if (gr == gcb + 1) f1 = 1.f;
      if (gr == gcb + 2) f2 = 1.f;
      if (gr == gcb + 3) f3 = 1.f;
      unsigned int u0 = bf16rne(f0) | (bf16rne(f1) << 16);
      unsigned int u1 = bf16rne(f2) | (bf16rne(f3) << 16);
      *(uint2*)&Al[row][acol] = make_uint2(u0, u1);
    }
    // ---- stage B tile (bf16 copy from hsT; K-tail rows pre-zeroed)
    #pragma unroll
    for (int it = 0; it < 8; ++it){
      int cc = it * 32 + bcol;
      *(uint4*)&Bl[cc][bko] = *(const uint4*)(hsT + (size_t)cc * MP + k0 + bko);
    }
    __syncthreads();
    // ---- MFMA: 2x8 fragments of 16x16, K-step 32
    #pragma unroll
    for (int kk = 0; kk < 64; kk += 32){
      short8x a0 = *(const short8x*)&Al[wr*32      + (lane & 15)][kk + (lane >> 4) * 8];
      short8x a1 = *(const short8x*)&Al[wr*32 + 16 + (lane & 15)][kk + (lane >> 4) * 8];
      #pragma unroll
      for (int ni = 0; ni < 8; ++ni){
        short8x b = *(const short8x*)&Bl[wc*128 + ni*16 + (lane & 15)][kk + (lane >> 4) * 8];
        acc[0][ni] = __builtin_amdgcn_mfma_f32_16x16x32_bf16(a0, b, acc[0][ni], 0, 0, 0);
        acc[1][ni] = __builtin_amdgcn_mfma_f32_16x16x32_bf16(a1, b, acc[1][ni], 0, 0, 0);
      }
    }
    __syncthreads();
  }
  // ---- epilogue: atomic accumulate partial K-sums (4 commutative adds/elem)
  #pragma unroll
  for (int mi = 0; mi < 2; ++mi){
    #pragma unroll
    for (int ni = 0; ni < 8; ++ni){
      int gc = wc*128 + ni*16 + (lane & 15);
      #pragma unroll
      for (int j = 0; j < 4; ++j){
        int gr = r0 + wr*32 + mi*16 + (lane >> 4) * 4 + j;
        if (gr < NROW) atomicAdd(out + (size_t)gr * NF + gc, acc[mi][ni][j]);
      }
    }
  }
}

// ---------------- k_epi: out = relu(dinv_i * acc + cb + eb), in place
__global__ void k_epi(float* __restrict__ out, const float* __restrict__ dinv,
                      const float* __restrict__ cb, const float* __restrict__ eb){
  int e = (blockIdx.x * 256 + threadIdx.x) * 4;
  int i = e >> 8, c = e & 255;
  float di = dinv[i];
  float4 v = *(float4*)(out + e);
  v.x = fmaxf(fmaf(v.x, di, cb[c+0] + eb[c+0]), 0.f);
  v.y = fmaxf(fmaf(v.y, di, cb[c+1] + eb[c+1]), 0.f);
  v.z = fmaxf(fmaf(v.z, di, cb[c+2] + eb[c+2]), 0.f);
  v.w = fmaxf(fmaf(v.w, di, cb[c+3] + eb[c+3]), 0.f);
  *(float4*)(out + e) = v;
}

extern "C" void kernel_launch(void* const* d_in, const int* in_sizes, int n_in,
                              void* d_out, int out_size, void* d_ws, size_t ws_size,
                              hipStream_t stream){
  const float* feat = (const float*)d_in[0];
  const float* adj  = (const float*)d_in[1];
  const float* W    = (const float*)d_in[2];
  const float* cb   = (const float*)d_in[3];
  const float* eb   = (const float*)d_in[4];
  float* out = (float*)d_out;

  // ws layout: degp f32[4][10048] @0 ; dinv f32[10048] @256KB ;
  //            hsT bf16[256][10048] @512KB. (no adjb anymore)
  float* degp = (float*)d_ws;
  float* dinv = (float*)((char*)d_ws + (256u << 10));
  unsigned short* hsT = (unsigned short*)((char*)d_ws + (512u << 10));

  k_zero <<<(NROW*NF)/1024,   256, 0, stream>>>((float4*)out);
  k_deg2 <<<dim3(NROW/4, 4),  256, 0, stream>>>(adj, degp);
  k_dinv <<<(MP + 255)/256,   256, 0, stream>>>(degp, adj, dinv, hsT);
  k_featw<<<NROW/8,           128, 0, stream>>>(feat, W, dinv, hsT);
  k_gemm <<<dim3(NTILES, 4),  256, 0, stream>>>(adj, hsT, out);
  k_epi  <<<(NROW*NF)/1024,   256, 0, stream>>>(out, dinv, cb, eb);
}